// Round 5
// baseline (932.290 us; speedup 1.0000x reference)
//
#include <hip/hip_runtime.h>
#include <hip/hip_bf16.h>
#include <math.h>

#define BB 8
#define TT 512
#define CC 512
#define HH 8
#define DH 64
#define LL 2
#define VV 512
#define NSTEPS 4
#define BT (BB*TT)
#define FF (4*CC)

typedef unsigned short u16;
typedef __bf16 bf16x8 __attribute__((ext_vector_type(8)));
typedef float f32x4 __attribute__((ext_vector_type(4)));
typedef u16 u16x8 __attribute__((ext_vector_type(8)));
typedef u16 u16x4 __attribute__((ext_vector_type(4)));

// fp32 -> bf16 bits, round-to-nearest-even
static __device__ __forceinline__ u16 f2bf(float f) {
    unsigned int u = __float_as_uint(f);
    unsigned int r = (u + 0x7fffu + ((u >> 16) & 1u)) >> 16;
    return (u16)r;
}

// async global->LDS, 16 bytes per lane (global_load_lds_dwordx4)
static __device__ __forceinline__ void async16(const void* g, void* l) {
    __builtin_amdgcn_global_load_lds((__attribute__((address_space(1))) void*)g,
                                     (__attribute__((address_space(3))) void*)l, 16, 0, 0);
}

// bank swizzle: row r's global chunk g lives at LDS chunk g ^ p(r) (source-side permute).
static __device__ __forceinline__ int swzp(int r) { return (r ^ (r >> 2)) & 7; }

// ---------------- merged prologue ----------------
// blocks [0,1536):    per-layer weight cast+transpose tiles (g folded at pack time)
// blocks [1536,1600): Whead cast+transpose (lnf_g folded)
// blocks [1600,1840): u/c column reductions, k-split x8 -> partials ucb[8][7680] (u), +61440 (c)
// blocks [1840,3888): embedding, 2 rows/block: x fp32, xb bf16, row stats partials
__global__ __launch_bounds__(256)
void prologue_kernel(const float* __restrict__ Wq, const float* __restrict__ Wk,
                     const float* __restrict__ Wv, const float* __restrict__ Wp,
                     const float* __restrict__ W1, const float* __restrict__ W2,
                     const float* __restrict__ Wh,
                     const float* __restrict__ ln1g, const float* __restrict__ ln1b,
                     const float* __restrict__ ln2g, const float* __restrict__ ln2b,
                     const float* __restrict__ lnfg, const float* __restrict__ lnfb,
                     u16* w_qkvt, u16* w_pt, u16* w_1t, u16* w_2t, u16* w_ht,
                     const int* __restrict__ idx, const float* __restrict__ tok,
                     const float* __restrict__ pos, float* __restrict__ x,
                     u16* __restrict__ xb, float* __restrict__ ucb,
                     float2* __restrict__ sp) {
    int bid = blockIdx.x;
    const size_t wcc = (size_t)CC*CC, wcf = (size_t)CC*FF;
    if (bid >= 1840) {
        // ---- embedding: 2 rows per block, vectorized ----
        int eb = bid - 1840;
        int t  = threadIdx.x;
        int r  = t >> 7, c4 = t & 127;
        int row = eb*2 + r;
        int token = idx[row];
        int posrow = row & (TT - 1);
        f32x4 v = ((const f32x4*)(tok + (size_t)token*CC))[c4]
                + ((const f32x4*)(pos + (size_t)posrow*CC))[c4];
        size_t base = (size_t)row*CC;
        ((f32x4*)(x + base))[c4] = v;
        u16x4 o;
#pragma unroll
        for (int j = 0; j < 4; j++) o[j] = f2bf(v[j]);
        *(u16x4*)&xb[base + c4*4] = o;
        float s = v[0]+v[1]+v[2]+v[3];
        float q = v[0]*v[0]+v[1]*v[1]+v[2]*v[2]+v[3]*v[3];
#pragma unroll
        for (int off = 1; off < 64; off <<= 1) { s += __shfl_xor(s, off); q += __shfl_xor(q, off); }
        __shared__ float rs[4], rq[4];
        int wid = t >> 6, lane = t & 63;
        if (lane == 0) { rs[wid] = s; rq[wid] = q; }
        __syncthreads();
        if (t < 16) {
            int r2 = t >> 3, slot = t & 7;
            float2 val = (slot == 0)
                ? make_float2(rs[r2*2] + rs[r2*2+1], rq[r2*2] + rq[r2*2+1])
                : make_float2(0.f, 0.f);
            sp[(size_t)(eb*2 + r2)*8 + slot] = val;
        }
        return;
    }
    if (bid >= 1600) {
        // ---- u/c partials: 240 blocks = 8 k-chunks x 30 col-blocks ----
        int d  = bid - 1600;
        int j  = d & 7;            // k chunk
        int cb = d >> 3;           // column block
        int c  = cb*256 + threadIdx.x;   // 0..7679
        const float* Wsrc; const float* gv; const float* bv2;
        int n, Nd;
        if (c < 3072) {                       // qkv: [l][mat][n]
            int l = c / 1536, w = c % 1536, m = w / 512; n = w % 512; Nd = CC;
            Wsrc = (m == 0 ? Wq : (m == 1 ? Wk : Wv)) + l*wcc;
            gv = ln1g + l*CC; bv2 = ln1b + l*CC;
        } else if (c < 7168) {                // fc1: [l][n]
            int dd = c - 3072, l = dd / 2048; n = dd % 2048; Nd = FF;
            Wsrc = W1 + l*wcf; gv = ln2g + l*CC; bv2 = ln2b + l*CC;
        } else {                              // head
            n = c - 7168; Nd = VV; Wsrc = Wh; gv = lnfg; bv2 = lnfb;
        }
        float su = 0.f, sc = 0.f;
        int k0 = j*64;
#pragma unroll 4
        for (int kk = 0; kk < 64; kk++) {
            float w = Wsrc[(size_t)(k0 + kk)*Nd + n];
            su += gv[k0 + kk]*w; sc += bv2[k0 + kk]*w;
        }
        ucb[j*7680 + c]         = su;
        ucb[61440 + j*7680 + c] = sc;
        return;
    }
    // ---- weight cast + transpose tiles ----
    const float* src; u16* dst; const float* gv = nullptr; int K, N, i0, j0;
    if (bid < 1536) {
        int l = bid / 768, r = bid % 768;
        if (r < 256) {
            int m = r / 64, t = r % 64;
            K = CC; N = CC;
            i0 = (t / 8) * 64; j0 = (t % 8) * 64;
            if      (m == 0) { src = Wq + l*wcc; dst = w_qkvt + (size_t)l*3*wcc;          gv = ln1g + l*CC; }
            else if (m == 1) { src = Wk + l*wcc; dst = w_qkvt + (size_t)l*3*wcc + wcc;    gv = ln1g + l*CC; }
            else if (m == 2) { src = Wv + l*wcc; dst = w_qkvt + (size_t)l*3*wcc + 2*wcc;  gv = ln1g + l*CC; }
            else             { src = Wp + l*wcc; dst = w_pt + (size_t)l*wcc; }
        } else if (r < 512) {
            int t = r - 256;               // W1: [CC][FF] -> [FF][CC]
            K = CC; N = FF;
            i0 = (t / 32) * 64; j0 = (t % 32) * 64;
            src = W1 + l*wcf; dst = w_1t + (size_t)l*wcf; gv = ln2g + l*CC;
        } else {
            int t = r - 512;               // W2: [FF][CC] -> [CC][FF]
            K = FF; N = CC;
            i0 = (t / 8) * 64; j0 = (t % 8) * 64;
            src = W2 + l*wcf; dst = w_2t + (size_t)l*wcf;
        }
    } else {
        int t = bid - 1536;
        K = CC; N = CC;
        i0 = (t / 8) * 64; j0 = (t % 8) * 64;
        src = Wh; dst = w_ht; gv = lnfg;
    }
    __shared__ float tile[64][65];
    __shared__ float gl[64];
    int tt = threadIdx.x;
    int rr = tt >> 2, cg = (tt & 3) * 16;
    if (tt < 64) gl[tt] = gv ? gv[i0 + tt] : 1.0f;
    {
        const float* srow = &src[(size_t)(i0 + rr) * N + j0 + cg];
        f32x4 v[4];
#pragma unroll
        for (int w = 0; w < 4; w++) v[w] = ((const f32x4*)srow)[w];
#pragma unroll
        for (int w = 0; w < 4; w++)
#pragma unroll
            for (int e = 0; e < 4; e++) tile[rr][cg + w*4 + e] = v[w][e];
    }
    __syncthreads();
    u16x8 o0, o1;
#pragma unroll
    for (int i = 0; i < 8; i++) o0[i] = f2bf(tile[cg + i][rr]     * gl[cg + i]);
#pragma unroll
    for (int i = 0; i < 8; i++) o1[i] = f2bf(tile[cg + 8 + i][rr] * gl[cg + 8 + i]);
    u16* drow = &dst[(size_t)(j0 + rr) * K + i0 + cg];
    *(u16x8*)drow       = o0;
    *(u16x8*)(drow + 8) = o1;
}

// ---------------- MFMA GEMM, dbuf BK=64, bank-swizzled, templated wave grid --------------
// out = A[M,K](bf16) @ Bt[N,K]^T.
// EPI 0: LN-folded, fused QKV (q pre-scaled; v transposed)      [consumes spin/uvec/cvec]
// EPI 1: bias + residual -> fp32 outf + bf16 outq + stats spout [produces spout]
// EPI 2: LN-folded, bias + exact GELU -> bf16 outq              [consumes]
// EPI 3: LN-folded, plain fp32 out                              [consumes]
template<int BM, int BN, int THREADS, int WROWS, int WCOLS, int EPI>
__global__ __launch_bounds__(THREADS, 6)
void gemm_bt_kernel(const u16* __restrict__ A, const u16* __restrict__ Bt,
                    int N, int K,
                    const float* __restrict__ bias, const float* __restrict__ biask,
                    const float* __restrict__ biasv,
                    const float* __restrict__ uvec, const float* __restrict__ cvec,
                    const float2* __restrict__ spin, float2* __restrict__ spout,
                    float* outf, u16* outq, u16* outk, u16* outvt) {
    constexpr int WTM = BM / WROWS, WTN = BN / WCOLS;
    constexpr int TM = WTM / 16, TN = WTN / 16;
    constexpr bool FOLD = (EPI == 0 || EPI == 2 || EPI == 3);
    static_assert(THREADS == WROWS * WCOLS * 64, "wave grid");
    static_assert((8*BM) % THREADS == 0 && (8*BN) % THREADS == 0, "staging divisibility");
    static_assert(EPI != 1 || (BM == 64 && BN == 64 && WROWS == 2 && WCOLS == 2), "stats layout");
    __shared__ u16 lds_a[2][2][BM][32];
    __shared__ u16 lds_b[2][2][BN][32];
    __shared__ float s_rs[FOLD ? BM : 1], s_mrs[FOLD ? BM : 1];
    __shared__ float psum[EPI == 1 ? 2 : 1][BM], psq[EPI == 1 ? 2 : 1][BM];
    int tid = threadIdx.x;
    int wid = tid >> 6, lane = tid & 63;
    int quad = lane >> 4, l15 = lane & 15;
    int wm = (wid % WROWS) * WTM, wn = (wid / WROWS) * WTN;

    // XCD swizzle: lin&7 picks bm residue -> all bn-blocks of a bm on one XCD
    int NBN = N / BN;
    int lin = blockIdx.x;
    int x8 = lin & 7, slot = lin >> 3;
    int bn = slot % NBN;
    int bm = (slot / NBN) * 8 + x8;

    const size_t a0 = (size_t)bm * BM, b0 = (size_t)bn * BN;

    auto stage = [&](int buf, int kt) {
#pragma unroll
        for (int i = 0; i < (8*BM)/THREADS; i++) {
            int f = tid + i*THREADS;
            int ks2 = f / (4*BM), rem = f % (4*BM);
            int row = rem >> 2, c2 = rem & 3;
            int g = (ks2*4 + c2) ^ swzp(row);
            async16(&A[(a0 + row)*K + kt + g*8], (u16*)lds_a[buf] + (size_t)f*8);
        }
#pragma unroll
        for (int i = 0; i < (8*BN)/THREADS; i++) {
            int f = tid + i*THREADS;
            int ks2 = f / (4*BN), rem = f % (4*BN);
            int row = rem >> 2, c2 = rem & 3;
            int g = (ks2*4 + c2) ^ swzp(row);
            async16(&Bt[(b0 + row)*K + kt + g*8], (u16*)lds_b[buf] + (size_t)f*8);
        }
    };

    f32x4 zero = {0.f, 0.f, 0.f, 0.f};
    f32x4 acc[TM][TN];
#pragma unroll
    for (int mi = 0; mi < TM; mi++)
#pragma unroll
        for (int ni = 0; ni < TN; ni++) acc[mi][ni] = zero;

    stage(0, 0);
    __syncthreads();
    const int NKT = K / 64;
    for (int kt = 0; kt < NKT; kt++) {
        int cur = kt & 1;
        if (kt + 1 < NKT) stage(cur ^ 1, (kt + 1) * 64);
#pragma unroll
        for (int ks = 0; ks < 2; ks++) {
            bf16x8 af[TM], bfr[TN];
#pragma unroll
            for (int mi = 0; mi < TM; mi++) {
                int row = wm + mi*16 + l15;
                int lc = (ks*4 + quad) ^ swzp(row);
                af[mi] = *(const bf16x8*)&lds_a[cur][lc >> 2][row][(lc & 3) * 8];
            }
#pragma unroll
            for (int ni = 0; ni < TN; ni++) {
                int row = wn + ni*16 + l15;
                int lc = (ks*4 + quad) ^ swzp(row);
                bfr[ni] = *(const bf16x8*)&lds_b[cur][lc >> 2][row][(lc & 3) * 8];
            }
#pragma unroll
            for (int mi = 0; mi < TM; mi++)
#pragma unroll
                for (int ni = 0; ni < TN; ni++)
                    acc[mi][ni] = __builtin_amdgcn_mfma_f32_16x16x32_bf16(af[mi], bfr[ni], acc[mi][ni], 0, 0, 0);
        }
        __syncthreads();
    }

    // LN-fold prep: reduce 8 per-row stats partials -> rstd, mu*rstd
    if (FOLD) {
        for (int r = tid; r < BM; r += THREADS) {
            float s = 0.f, q = 0.f;
#pragma unroll
            for (int j = 0; j < 8; j++) { float2 p = spin[(a0 + r)*8 + j]; s += p.x; q += p.y; }
            float mu  = s * (1.0f / CC);
            float var = q * (1.0f / CC) - mu * mu;
            float rstd = rsqrtf(var + 1e-5f);
            s_rs[r] = rstd; s_mrs[r] = mu * rstd;
        }
        __syncthreads();
    }

    float lsum[TM][4], lsq[TM][4];
    if (EPI == 1) {
#pragma unroll
        for (int mi = 0; mi < TM; mi++)
#pragma unroll
            for (int i = 0; i < 4; i++) { lsum[mi][i] = 0.f; lsq[mi][i] = 0.f; }
    }

#pragma unroll
    for (int mi = 0; mi < TM; mi++)
#pragma unroll
        for (int ni = 0; ni < TN; ni++) {
            int col = bn*BN + wn + ni*16 + l15;
            float uc_ = 0.f, cc_ = 0.f;
            if (FOLD) {
#pragma unroll
                for (int j = 0; j < 8; j++) { uc_ += uvec[j*7680 + col]; cc_ += cvec[j*7680 + col]; }
            }
#pragma unroll
            for (int i = 0; i < 4; i++) {
                int rloc = wm + mi*16 + quad*4 + i;
                int row = bm*BM + rloc;
                float v = acc[mi][ni][i];
                if (FOLD) v = s_rs[rloc]*v - s_mrs[rloc]*uc_ + cc_;
                if (EPI == 0) {
                    int region = col >> 9, cl = col & 511;
                    if (region == 0) {
                        v = (v + bias[cl]) * 0.125f;   // fold 1/sqrt(64) into q
                        outq[(size_t)row*512 + cl] = f2bf(v);
                    } else if (region == 1) {
                        v += biask[cl];
                        outk[(size_t)row*512 + cl] = f2bf(v);
                    } else {
                        v += biasv[cl];
                        int bb = row >> 9, tpos = row & 511, hh = cl >> 6, dh = cl & 63;
                        outvt[(((size_t)(bb*8 + hh)*64 + dh) << 9) + tpos] = f2bf(v);
                    }
                } else if (EPI == 1) {
                    size_t id2 = (size_t)row * N + col;
                    v += bias[col] + outf[id2];
                    outf[id2] = v;
                    outq[id2] = f2bf(v);
                    lsum[mi][i] += v; lsq[mi][i] += v*v;
                } else if (EPI == 2) {
                    v += bias[col];
                    v = 0.5f * v * (1.0f + erff(v * 0.70710678118654752f));
                    outq[(size_t)row * N + col] = f2bf(v);
                } else {
                    outf[(size_t)row * N + col] = v;
                }
            }
        }

    if (EPI == 1) {
        // per-row partial (sum, sumsq) over this block's 64-col span -> spout slot bn
#pragma unroll
        for (int mi = 0; mi < TM; mi++)
#pragma unroll
            for (int i = 0; i < 4; i++) {
                float s = lsum[mi][i], q = lsq[mi][i];
#pragma unroll
                for (int off = 1; off < 16; off <<= 1) { s += __shfl_xor(s, off); q += __shfl_xor(q, off); }
                if (l15 == 0) {
                    int pr = wm + mi*16 + quad*4 + i;
                    psum[wn >> 5][pr] = s; psq[wn >> 5][pr] = q;
                }
            }
        __syncthreads();
        if (tid < BM) {
            spout[(a0 + tid)*8 + bn] = make_float2(psum[0][tid] + psum[1][tid],
                                                   psq[0][tid] + psq[1][tid]);
        }
    }
}

// ---------------- fused MFMA flash attention, SWAPPED QK^T (per-lane softmax) ------------
// S^T = mfma(K_frag, Q_frag): lane l15 = q, regs = k. Each lane owns 16 scores of ONE
// q-row -> softmax is per-lane serial + 2 cross-quad shfls; P packed as 4x8B LDS writes.
__global__ __launch_bounds__(256)
void attn_mfma_kernel(const u16* __restrict__ q, const u16* __restrict__ k,
                      const u16* __restrict__ vt, u16* __restrict__ y) {
    __shared__ u16 lq[64][64];
    __shared__ u16 lk[2][64][64];
    __shared__ u16 lv[2][64][64];
    __shared__ u16 lp[4][16][72];
    int qt = blockIdx.x, h = blockIdx.y, b = blockIdx.z;
    int tid = threadIdx.x;
    int wid = tid >> 6, lane = tid & 63;
    int quad = lane >> 4, l15 = lane & 15;
    const int sr = tid >> 3;
    const int sc = (tid & 7) * 8;
    const int gsc = (((tid & 7) ^ swzp(sr)) << 3);

    auto stageKV = [&](int buf, int kt) {
#pragma unroll
        for (int c = 0; c < 2; c++) {
            async16(&k[(size_t)(b*TT + kt*64 + c*32 + sr)*CC + h*DH + gsc], &lk[buf][c*32 + sr][sc]);
            async16(&vt[((size_t)((b*HH + h)*DH + c*32 + sr))*TT + kt*64 + gsc], &lv[buf][c*32 + sr][sc]);
        }
    };

#pragma unroll
    for (int c = 0; c < 2; c++)
        async16(&q[(size_t)(b*TT + qt*64 + c*32 + sr)*CC + h*DH + gsc], &lq[c*32 + sr][sc]);
    stageKV(0, 0);
    __syncthreads();

    f32x4 zero = {0.f, 0.f, 0.f, 0.f};
    f32x4 acc_o[4];
    float m_q = -INFINITY, l_q = 0.f;      // state for q-row = wid*16 + l15
#pragma unroll
    for (int ni = 0; ni < 4; ni++) acc_o[ni] = zero;

    const int rowq = wid*16 + l15;
    const int pq = swzp(rowq);

    for (int kt = 0; kt < TT/64; kt++) {
        int cur = kt & 1;
        if (kt + 1 < TT/64) stageKV(cur ^ 1, kt + 1);

        f32x4 s[4];
#pragma unroll
        for (int ni = 0; ni < 4; ni++) s[ni] = zero;
#pragma unroll
        for (int ks = 0; ks < 2; ks++) {
            int lcq = (ks*4 + quad) ^ pq;
            bf16x8 aq = *(const bf16x8*)&lq[rowq][lcq * 8];
            bf16x8 bfr[4];
#pragma unroll
            for (int ni = 0; ni < 4; ni++) {
                int rowk = ni*16 + l15;
                int lck = (ks*4 + quad) ^ swzp(rowk);
                bfr[ni] = *(const bf16x8*)&lk[cur][rowk][lck * 8];
            }
            // SWAPPED: A = K rows, B = Q rows  ->  D[k][q], col(l15) = q
#pragma unroll
            for (int ni = 0; ni < 4; ni++)
                s[ni] = __builtin_amdgcn_mfma_f32_16x16x32_bf16(bfr[ni], aq, s[ni], 0, 0, 0);
        }

        // per-lane online softmax over this lane's 16 scores (k = ni*16 + quad*4 + i)
        float mx = s[0][0];
#pragma unroll
        for (int ni = 0; ni < 4; ni++)
#pragma unroll
            for (int i = 0; i < 4; i++) mx = fmaxf(mx, s[ni][i]);
        mx = fmaxf(mx, __shfl_xor(mx, 16));
        mx = fmaxf(mx, __shfl_xor(mx, 32));
        float mn = fmaxf(m_q, mx);
        float al = __expf(m_q - mn);
        float rs = 0.f;
#pragma unroll
        for (int ni = 0; ni < 4; ni++)
#pragma unroll
            for (int i = 0; i < 4; i++) {
                float p = __expf(s[ni][i] - mn);
                s[ni][i] = p;
                rs += p;
            }
        rs += __shfl_xor(rs, 16);
        rs += __shfl_xor(rs, 32);
        l_q = l_q * al + rs;
        m_q = mn;

        // broadcast al from lane q'=quad*4+i (lanes 0..15 hold reduced values)
        float alb[4];
#pragma unroll
        for (int i = 0; i < 4; i++) alb[i] = __shfl(al, quad*4 + i);
#pragma unroll
        for (int ni = 0; ni < 4; ni++)
#pragma unroll
            for (int i = 0; i < 4; i++) acc_o[ni][i] *= alb[i];

        // P^T in regs -> lp[q][k]: lane writes 4 u16 per ni, packed 8B
#pragma unroll
        for (int ni = 0; ni < 4; ni++) {
            u16x4 o;
#pragma unroll
            for (int i = 0; i < 4; i++) o[i] = f2bf(s[ni][i]);
            *(u16x4*)&lp[wid][l15][ni*16 + quad*4] = o;
        }

#pragma unroll
        for (int ks = 0; ks < 2; ks++) {
            bf16x8 pa = *(const bf16x8*)&lp[wid][l15][ks*32 + quad*8];
            bf16x8 vb[4];
#pragma unroll
            for (int ni = 0; ni < 4; ni++) {
                int rowv = ni*16 + l15;
                int lcv = (ks*4 + quad) ^ swzp(rowv);
                vb[ni] = *(const bf16x8*)&lv[cur][rowv][lcv * 8];
            }
#pragma unroll
            for (int ni = 0; ni < 4; ni++)
                acc_o[ni] = __builtin_amdgcn_mfma_f32_16x16x32_bf16(pa, vb[ni], acc_o[ni], 0, 0, 0);
        }
        __syncthreads();
    }

    float lb[4];
#pragma unroll
    for (int i = 0; i < 4; i++) lb[i] = __shfl(l_q, quad*4 + i);
#pragma unroll
    for (int i = 0; i < 4; i++) {
        float inv = 1.0f / lb[i];
#pragma unroll
        for (int ni = 0; ni < 4; ni++) {
            int qrow = qt*64 + wid*16 + quad*4 + i;
            int col  = h*DH + ni*16 + l15;
            y[(size_t)(b*TT + qrow)*CC + col] = f2bf(acc_o[ni][i] * inv);
        }
    }
}

extern "C" void kernel_launch(void* const* d_in, const int* in_sizes, int n_in,
                              void* d_out, int out_size, void* d_ws, size_t ws_size,
                              hipStream_t stream) {
    const int*   idx   = (const int*)d_in[0];
    const float* tok   = (const float*)d_in[1];
    const float* pos   = (const float*)d_in[2];
    const float* ln1g  = (const float*)d_in[3];
    const float* ln1b  = (const float*)d_in[4];
    const float* Wq    = (const float*)d_in[5];
    const float* bq    = (const float*)d_in[6];
    const float* Wk    = (const float*)d_in[7];
    const float* bk    = (const float*)d_in[8];
    const float* Wv    = (const float*)d_in[9];
    const float* bv    = (const float*)d_in[10];
    const float* Wp    = (const float*)d_in[11];
    const float* bp    = (const float*)d_in[12];
    const float* ln2g  = (const float*)d_in[13];
    const float* ln2b  = (const float*)d_in[14];
    const float* W1    = (const float*)d_in[15];
    const float* b1    = (const float*)d_in[16];
    const float* W2    = (const float*)d_in[17];
    const float* b2    = (const float*)d_in[18];
    const float* lnfg  = (const float*)d_in[19];
    const float* lnfb  = (const float*)d_in[20];
    const float* Whead = (const float*)d_in[21];

    // ---- workspace layout ----
    float* x  = (float*)d_ws;                       // BT*CC fp32 residual master
    u16* xb   = (u16*)(x + (size_t)BT*CC);          // BT*CC bf16 raw-x copy (LN folded downstream)
    u16* yb   = xb + (size_t)BT*CC;                 // attn output
    u16* R    = yb + (size_t)BT*CC;
    u16* qb   = R;
    u16* kb   = R + (size_t)BT*CC;
    u16* vtb  = R + (size_t)2*BT*CC;
    u16* hb   = R;                                  // BT*FF spans region (q/k/vt dead in MLP)
    u16* w_qkvt = R + (size_t)4*BT*CC;
    u16* w_pt   = w_qkvt + (size_t)2*3*CC*CC;
    u16* w_1t   = w_pt   + (size_t)2*CC*CC;
    u16* w_2t   = w_1t   + (size_t)2*CC*FF;
    u16* w_ht   = w_2t   + (size_t)2*FF*CC;
    float* ucb  = (float*)(w_ht + (size_t)CC*VV);   // 2*8*7680 floats: u/c k-split partials
    float2* sp  = (float2*)(ucb + 2*8*7680);        // BT*8 row-stats partials

    prologue_kernel<<<1840 + BT/2, 256, 0, stream>>>(Wq, Wk, Wv, Wp, W1, W2, Whead,
                                                     ln1g, ln1b, ln2g, ln2b, lnfg, lnfb,
                                                     w_qkvt, w_pt, w_1t, w_2t, w_ht,
                                                     idx, tok, pos, x, xb, ucb, sp);

    const int g_qkv  = (3*CC/128) * (BT/64);   // 12*64  = 768  (512t)
    const int g_fc1  = (FF/128)   * (BT/64);   // 16*64  = 1024 (512t)
    const int g_pf   = (CC/64)    * (BT/64);   // 8*64   = 512  (256t, proj/fc2, 64x64)
    const int g_head = (VV/64)    * (BT/64);   // 512

    for (int s = 0; s < NSTEPS; s++) {
        for (int l = 0; l < LL; l++) {
            // attention: LN1 folded into QKV GEMM
            gemm_bt_kernel<64,128,512,2,4,0><<<g_qkv, 512, 0, stream>>>(
                xb, w_qkvt + (size_t)l*3*CC*CC, 3*CC, CC,
                bq + l*CC, bk + l*CC, bv + l*CC,
                ucb + l*1536, ucb + 61440 + l*1536, sp, nullptr,
                nullptr, qb, kb, vtb);
            attn_mfma_kernel<<<dim3(TT/64, HH, BB), 256, 0, stream>>>(qb, kb, vtb, yb);
            gemm_bt_kernel<64,64,256,2,2,1><<<g_pf, 256, 0, stream>>>(
                yb, w_pt + (size_t)l*CC*CC, CC, CC,
                bp + l*CC, nullptr, nullptr,
                nullptr, nullptr, nullptr, sp,
                x, xb, nullptr, nullptr);
            // MLP: LN2 folded into fc1 GEMM
            gemm_bt_kernel<64,128,512,2,4,2><<<g_fc1, 512, 0, stream>>>(
                xb, w_1t + (size_t)l*CC*FF, FF, CC,
                b1 + (size_t)l*FF, nullptr, nullptr,
                ucb + 3072 + l*2048, ucb + 61440 + 3072 + l*2048, sp, nullptr,
                nullptr, hb, nullptr, nullptr);
            gemm_bt_kernel<64,64,256,2,2,1><<<g_pf, 256, 0, stream>>>(
                hb, w_2t + (size_t)l*FF*CC, CC, FF,
                b2 + l*CC, nullptr, nullptr,
                nullptr, nullptr, nullptr, sp,
                x, xb, nullptr, nullptr);
        }
    }

    // final LN folded into head GEMM (fp32 logits)
    gemm_bt_kernel<64,64,256,2,2,3><<<g_head, 256, 0, stream>>>(
        xb, w_ht, VV, CC,
        nullptr, nullptr, nullptr,
        ucb + 7168, ucb + 61440 + 7168, sp, nullptr,
        (float*)d_out, nullptr, nullptr, nullptr);
}

// Round 6
// 834.503 us; speedup vs baseline: 1.1172x; 1.1172x over previous
//
#include <hip/hip_runtime.h>
#include <hip/hip_bf16.h>
#include <math.h>

#define BB 8
#define TT 512
#define CC 512
#define HH 8
#define DH 64
#define LL 2
#define VV 512
#define NSTEPS 4
#define BT (BB*TT)
#define FF (4*CC)

typedef unsigned short u16;
typedef __bf16 bf16x8 __attribute__((ext_vector_type(8)));
typedef float f32x4 __attribute__((ext_vector_type(4)));
typedef u16 u16x8 __attribute__((ext_vector_type(8)));
typedef u16 u16x4 __attribute__((ext_vector_type(4)));

// fp32 -> bf16 bits, round-to-nearest-even
static __device__ __forceinline__ u16 f2bf(float f) {
    unsigned int u = __float_as_uint(f);
    unsigned int r = (u + 0x7fffu + ((u >> 16) & 1u)) >> 16;
    return (u16)r;
}

// async global->LDS, 16 bytes per lane (global_load_lds_dwordx4)
static __device__ __forceinline__ void async16(const void* g, void* l) {
    __builtin_amdgcn_global_load_lds((__attribute__((address_space(1))) void*)g,
                                     (__attribute__((address_space(3))) void*)l, 16, 0, 0);
}

// bank swizzle: row r's global chunk g lives at LDS chunk g ^ p(r) (source-side permute).
static __device__ __forceinline__ int swzp(int r) { return (r ^ (r >> 2)) & 7; }

// ---------------- merged prologue ----------------
// blocks [0,1536):    per-layer weight cast+transpose tiles (g folded at pack time)
// blocks [1536,1600): Whead cast+transpose (lnf_g folded)
// blocks [1600,1840): u/c column reductions, k-split x8 -> partials ucb[8][7680] (u), +61440 (c)
// blocks [1840,3888): embedding, 2 rows/block: x fp32, xb bf16, row stats partials
__global__ __launch_bounds__(256)
void prologue_kernel(const float* __restrict__ Wq, const float* __restrict__ Wk,
                     const float* __restrict__ Wv, const float* __restrict__ Wp,
                     const float* __restrict__ W1, const float* __restrict__ W2,
                     const float* __restrict__ Wh,
                     const float* __restrict__ ln1g, const float* __restrict__ ln1b,
                     const float* __restrict__ ln2g, const float* __restrict__ ln2b,
                     const float* __restrict__ lnfg, const float* __restrict__ lnfb,
                     u16* w_qkvt, u16* w_pt, u16* w_1t, u16* w_2t, u16* w_ht,
                     const int* __restrict__ idx, const float* __restrict__ tok,
                     const float* __restrict__ pos, float* __restrict__ x,
                     u16* __restrict__ xb, float* __restrict__ ucb,
                     float2* __restrict__ sp) {
    int bid = blockIdx.x;
    const size_t wcc = (size_t)CC*CC, wcf = (size_t)CC*FF;
    if (bid >= 1840) {
        // ---- embedding: 2 rows per block, vectorized ----
        int eb = bid - 1840;
        int t  = threadIdx.x;
        int r  = t >> 7, c4 = t & 127;
        int row = eb*2 + r;
        int token = idx[row];
        int posrow = row & (TT - 1);
        f32x4 v = ((const f32x4*)(tok + (size_t)token*CC))[c4]
                + ((const f32x4*)(pos + (size_t)posrow*CC))[c4];
        size_t base = (size_t)row*CC;
        ((f32x4*)(x + base))[c4] = v;
        u16x4 o;
#pragma unroll
        for (int j = 0; j < 4; j++) o[j] = f2bf(v[j]);
        *(u16x4*)&xb[base + c4*4] = o;
        float s = v[0]+v[1]+v[2]+v[3];
        float q = v[0]*v[0]+v[1]*v[1]+v[2]*v[2]+v[3]*v[3];
#pragma unroll
        for (int off = 1; off < 64; off <<= 1) { s += __shfl_xor(s, off); q += __shfl_xor(q, off); }
        __shared__ float rs[4], rq[4];
        int wid = t >> 6, lane = t & 63;
        if (lane == 0) { rs[wid] = s; rq[wid] = q; }
        __syncthreads();
        if (t < 16) {
            int r2 = t >> 3, slot = t & 7;
            float2 val = (slot == 0)
                ? make_float2(rs[r2*2] + rs[r2*2+1], rq[r2*2] + rq[r2*2+1])
                : make_float2(0.f, 0.f);
            sp[(size_t)(eb*2 + r2)*8 + slot] = val;
        }
        return;
    }
    if (bid >= 1600) {
        // ---- u/c partials: 240 blocks = 8 k-chunks x 30 col-blocks ----
        int d  = bid - 1600;
        int j  = d & 7;            // k chunk
        int cb = d >> 3;           // column block
        int c  = cb*256 + threadIdx.x;   // 0..7679
        const float* Wsrc; const float* gv; const float* bv2;
        int n, Nd;
        if (c < 3072) {                       // qkv: [l][mat][n]
            int l = c / 1536, w = c % 1536, m = w / 512; n = w % 512; Nd = CC;
            Wsrc = (m == 0 ? Wq : (m == 1 ? Wk : Wv)) + l*wcc;
            gv = ln1g + l*CC; bv2 = ln1b + l*CC;
        } else if (c < 7168) {                // fc1: [l][n]
            int dd = c - 3072, l = dd / 2048; n = dd % 2048; Nd = FF;
            Wsrc = W1 + l*wcf; gv = ln2g + l*CC; bv2 = ln2b + l*CC;
        } else {                              // head
            n = c - 7168; Nd = VV; Wsrc = Wh; gv = lnfg; bv2 = lnfb;
        }
        float su = 0.f, sc = 0.f;
        int k0 = j*64;
#pragma unroll 4
        for (int kk = 0; kk < 64; kk++) {
            float w = Wsrc[(size_t)(k0 + kk)*Nd + n];
            su += gv[k0 + kk]*w; sc += bv2[k0 + kk]*w;
        }
        ucb[j*7680 + c]         = su;
        ucb[61440 + j*7680 + c] = sc;
        return;
    }
    // ---- weight cast + transpose tiles ----
    const float* src; u16* dst; const float* gv = nullptr; int K, N, i0, j0;
    if (bid < 1536) {
        int l = bid / 768, r = bid % 768;
        if (r < 256) {
            int m = r / 64, t = r % 64;
            K = CC; N = CC;
            i0 = (t / 8) * 64; j0 = (t % 8) * 64;
            if      (m == 0) { src = Wq + l*wcc; dst = w_qkvt + (size_t)l*3*wcc;          gv = ln1g + l*CC; }
            else if (m == 1) { src = Wk + l*wcc; dst = w_qkvt + (size_t)l*3*wcc + wcc;    gv = ln1g + l*CC; }
            else if (m == 2) { src = Wv + l*wcc; dst = w_qkvt + (size_t)l*3*wcc + 2*wcc;  gv = ln1g + l*CC; }
            else             { src = Wp + l*wcc; dst = w_pt + (size_t)l*wcc; }
        } else if (r < 512) {
            int t = r - 256;               // W1: [CC][FF] -> [FF][CC]
            K = CC; N = FF;
            i0 = (t / 32) * 64; j0 = (t % 32) * 64;
            src = W1 + l*wcf; dst = w_1t + (size_t)l*wcf; gv = ln2g + l*CC;
        } else {
            int t = r - 512;               // W2: [FF][CC] -> [CC][FF]
            K = FF; N = CC;
            i0 = (t / 8) * 64; j0 = (t % 8) * 64;
            src = W2 + l*wcf; dst = w_2t + (size_t)l*wcf;
        }
    } else {
        int t = bid - 1536;
        K = CC; N = CC;
        i0 = (t / 8) * 64; j0 = (t % 8) * 64;
        src = Wh; dst = w_ht; gv = lnfg;
    }
    __shared__ float tile[64][65];
    __shared__ float gl[64];
    int tt = threadIdx.x;
    int rr = tt >> 2, cg = (tt & 3) * 16;
    if (tt < 64) gl[tt] = gv ? gv[i0 + tt] : 1.0f;
    {
        const float* srow = &src[(size_t)(i0 + rr) * N + j0 + cg];
        f32x4 v[4];
#pragma unroll
        for (int w = 0; w < 4; w++) v[w] = ((const f32x4*)srow)[w];
#pragma unroll
        for (int w = 0; w < 4; w++)
#pragma unroll
            for (int e = 0; e < 4; e++) tile[rr][cg + w*4 + e] = v[w][e];
    }
    __syncthreads();
    u16x8 o0, o1;
#pragma unroll
    for (int i = 0; i < 8; i++) o0[i] = f2bf(tile[cg + i][rr]     * gl[cg + i]);
#pragma unroll
    for (int i = 0; i < 8; i++) o1[i] = f2bf(tile[cg + 8 + i][rr] * gl[cg + 8 + i]);
    u16* drow = &dst[(size_t)(j0 + rr) * K + i0 + cg];
    *(u16x8*)drow       = o0;
    *(u16x8*)(drow + 8) = o1;
}

// ---------------- MFMA GEMM, dbuf BK=64, bank-swizzled, templated wave grid --------------
// out = A[M,K](bf16) @ Bt[N,K]^T.
// EPI 0: LN-folded, fused QKV (q pre-scaled; v transposed)      [consumes spin/uvec/cvec]
// EPI 1: bias + residual -> fp32 outf + bf16 outq + stats spout [produces spout]
// EPI 2: LN-folded, bias + exact GELU -> bf16 outq              [consumes]
// EPI 3: LN-folded, plain fp32 out                              [consumes]
template<int BM, int BN, int THREADS, int WROWS, int WCOLS, int EPI>
__global__ __launch_bounds__(THREADS, 6)
void gemm_bt_kernel(const u16* __restrict__ A, const u16* __restrict__ Bt,
                    int N, int K,
                    const float* __restrict__ bias, const float* __restrict__ biask,
                    const float* __restrict__ biasv,
                    const float* __restrict__ uvec, const float* __restrict__ cvec,
                    const float2* __restrict__ spin, float2* __restrict__ spout,
                    float* outf, u16* outq, u16* outk, u16* outvt) {
    constexpr int WTM = BM / WROWS, WTN = BN / WCOLS;
    constexpr int TM = WTM / 16, TN = WTN / 16;
    constexpr bool FOLD = (EPI == 0 || EPI == 2 || EPI == 3);
    static_assert(THREADS == WROWS * WCOLS * 64, "wave grid");
    static_assert((8*BM) % THREADS == 0 && (8*BN) % THREADS == 0, "staging divisibility");
    static_assert(EPI != 1 || (BM == 32 && BN == 64 && WROWS == 2 && WCOLS == 2), "stats layout");
    __shared__ u16 lds_a[2][2][BM][32];
    __shared__ u16 lds_b[2][2][BN][32];
    __shared__ float s_rs[FOLD ? BM : 1], s_mrs[FOLD ? BM : 1];
    __shared__ float psum[EPI == 1 ? 2 : 1][BM], psq[EPI == 1 ? 2 : 1][BM];
    int tid = threadIdx.x;
    int wid = tid >> 6, lane = tid & 63;
    int quad = lane >> 4, l15 = lane & 15;
    int wm = (wid % WROWS) * WTM, wn = (wid / WROWS) * WTN;

    // XCD swizzle: lin&7 picks bm residue -> all bn-blocks of a bm on one XCD
    int NBN = N / BN;
    int lin = blockIdx.x;
    int x8 = lin & 7, slot = lin >> 3;
    int bn = slot % NBN;
    int bm = (slot / NBN) * 8 + x8;

    const size_t a0 = (size_t)bm * BM, b0 = (size_t)bn * BN;

    auto stage = [&](int buf, int kt) {
#pragma unroll
        for (int i = 0; i < (8*BM)/THREADS; i++) {
            int f = tid + i*THREADS;
            int ks2 = f / (4*BM), rem = f % (4*BM);
            int row = rem >> 2, c2 = rem & 3;
            int g = (ks2*4 + c2) ^ swzp(row);
            async16(&A[(a0 + row)*K + kt + g*8], (u16*)lds_a[buf] + (size_t)f*8);
        }
#pragma unroll
        for (int i = 0; i < (8*BN)/THREADS; i++) {
            int f = tid + i*THREADS;
            int ks2 = f / (4*BN), rem = f % (4*BN);
            int row = rem >> 2, c2 = rem & 3;
            int g = (ks2*4 + c2) ^ swzp(row);
            async16(&Bt[(b0 + row)*K + kt + g*8], (u16*)lds_b[buf] + (size_t)f*8);
        }
    };

    f32x4 zero = {0.f, 0.f, 0.f, 0.f};
    f32x4 acc[TM][TN];
#pragma unroll
    for (int mi = 0; mi < TM; mi++)
#pragma unroll
        for (int ni = 0; ni < TN; ni++) acc[mi][ni] = zero;

    stage(0, 0);
    __syncthreads();
    const int NKT = K / 64;
    for (int kt = 0; kt < NKT; kt++) {
        int cur = kt & 1;
        if (kt + 1 < NKT) stage(cur ^ 1, (kt + 1) * 64);
#pragma unroll
        for (int ks = 0; ks < 2; ks++) {
            bf16x8 af[TM], bfr[TN];
#pragma unroll
            for (int mi = 0; mi < TM; mi++) {
                int row = wm + mi*16 + l15;
                int lc = (ks*4 + quad) ^ swzp(row);
                af[mi] = *(const bf16x8*)&lds_a[cur][lc >> 2][row][(lc & 3) * 8];
            }
#pragma unroll
            for (int ni = 0; ni < TN; ni++) {
                int row = wn + ni*16 + l15;
                int lc = (ks*4 + quad) ^ swzp(row);
                bfr[ni] = *(const bf16x8*)&lds_b[cur][lc >> 2][row][(lc & 3) * 8];
            }
#pragma unroll
            for (int mi = 0; mi < TM; mi++)
#pragma unroll
                for (int ni = 0; ni < TN; ni++)
                    acc[mi][ni] = __builtin_amdgcn_mfma_f32_16x16x32_bf16(af[mi], bfr[ni], acc[mi][ni], 0, 0, 0);
        }
        __syncthreads();
    }

    // LN-fold prep: reduce 8 per-row stats partials -> rstd, mu*rstd
    if (FOLD) {
        for (int r = tid; r < BM; r += THREADS) {
            float s = 0.f, q = 0.f;
#pragma unroll
            for (int j = 0; j < 8; j++) { float2 p = spin[(a0 + r)*8 + j]; s += p.x; q += p.y; }
            float mu  = s * (1.0f / CC);
            float var = q * (1.0f / CC) - mu * mu;
            float rstd = rsqrtf(var + 1e-5f);
            s_rs[r] = rstd; s_mrs[r] = mu * rstd;
        }
        __syncthreads();
    }

    float lsum[TM][4], lsq[TM][4];
    if (EPI == 1) {
#pragma unroll
        for (int mi = 0; mi < TM; mi++)
#pragma unroll
            for (int i = 0; i < 4; i++) { lsum[mi][i] = 0.f; lsq[mi][i] = 0.f; }
    }

#pragma unroll
    for (int mi = 0; mi < TM; mi++)
#pragma unroll
        for (int ni = 0; ni < TN; ni++) {
            int col = bn*BN + wn + ni*16 + l15;
            float uc_ = 0.f, cc_ = 0.f;
            if (FOLD) {
#pragma unroll
                for (int j = 0; j < 8; j++) { uc_ += uvec[j*7680 + col]; cc_ += cvec[j*7680 + col]; }
            }
            if (EPI == 0 && (col >> 9) == 2) {
                // v region: 4 consecutive tpos per lane -> one 8B packed store
                int cl = col & 511;
                int row0 = bm*BM + wm + mi*16 + quad*4;
                u16x4 o;
#pragma unroll
                for (int i = 0; i < 4; i++) {
                    int rloc = wm + mi*16 + quad*4 + i;
                    float v = s_rs[rloc]*acc[mi][ni][i] - s_mrs[rloc]*uc_ + cc_ + biasv[cl];
                    o[i] = f2bf(v);
                }
                int bb = row0 >> 9, tpos = row0 & 511, hh = cl >> 6, dh = cl & 63;
                *(u16x4*)&outvt[(((size_t)(bb*8 + hh)*64 + dh) << 9) + tpos] = o;
                continue;
            }
#pragma unroll
            for (int i = 0; i < 4; i++) {
                int rloc = wm + mi*16 + quad*4 + i;
                int row = bm*BM + rloc;
                float v = acc[mi][ni][i];
                if (FOLD) v = s_rs[rloc]*v - s_mrs[rloc]*uc_ + cc_;
                if (EPI == 0) {
                    int region = col >> 9, cl = col & 511;
                    if (region == 0) {
                        v = (v + bias[cl]) * 0.125f;   // fold 1/sqrt(64) into q
                        outq[(size_t)row*512 + cl] = f2bf(v);
                    } else {
                        v += biask[cl];
                        outk[(size_t)row*512 + cl] = f2bf(v);
                    }
                } else if (EPI == 1) {
                    size_t id2 = (size_t)row * N + col;
                    v += bias[col] + outf[id2];
                    outf[id2] = v;
                    outq[id2] = f2bf(v);
                    lsum[mi][i] += v; lsq[mi][i] += v*v;
                } else if (EPI == 2) {
                    v += bias[col];
                    v = 0.5f * v * (1.0f + erff(v * 0.70710678118654752f));
                    outq[(size_t)row * N + col] = f2bf(v);
                } else {
                    outf[(size_t)row * N + col] = v;
                }
            }
        }

    if (EPI == 1) {
        // per-row partial (sum, sumsq) over this block's 64-col span -> spout slot bn
#pragma unroll
        for (int mi = 0; mi < TM; mi++)
#pragma unroll
            for (int i = 0; i < 4; i++) {
                float s = lsum[mi][i], q = lsq[mi][i];
#pragma unroll
                for (int off = 1; off < 16; off <<= 1) { s += __shfl_xor(s, off); q += __shfl_xor(q, off); }
                if (l15 == 0) {
                    int pr = wm + mi*16 + quad*4 + i;
                    psum[wn >> 5][pr] = s; psq[wn >> 5][pr] = q;
                }
            }
        __syncthreads();
        if (tid < BM) {
            spout[(a0 + tid)*8 + bn] = make_float2(psum[0][tid] + psum[1][tid],
                                                   psq[0][tid] + psq[1][tid]);
        }
    }
}

// ---------------- fused MFMA flash attention, SWAPPED QK^T (per-lane softmax) ------------
// S^T = mfma(K_frag, Q_frag): lane l15 = q, regs = k. Each lane owns 16 scores of ONE
// q-row -> softmax is per-lane serial + 2 cross-quad shfls; P packed as 4x8B LDS writes.
// + defer-max (skip O-rescale while max growth <= 8) + setprio around MFMA clusters.
__global__ __launch_bounds__(256)
void attn_mfma_kernel(const u16* __restrict__ q, const u16* __restrict__ k,
                      const u16* __restrict__ vt, u16* __restrict__ y) {
    __shared__ u16 lq[64][64];
    __shared__ u16 lk[2][64][64];
    __shared__ u16 lv[2][64][64];
    __shared__ u16 lp[4][16][72];
    int qt = blockIdx.x, h = blockIdx.y, b = blockIdx.z;
    int tid = threadIdx.x;
    int wid = tid >> 6, lane = tid & 63;
    int quad = lane >> 4, l15 = lane & 15;
    const int sr = tid >> 3;
    const int sc = (tid & 7) * 8;
    const int gsc = (((tid & 7) ^ swzp(sr)) << 3);

    auto stageKV = [&](int buf, int kt) {
#pragma unroll
        for (int c = 0; c < 2; c++) {
            async16(&k[(size_t)(b*TT + kt*64 + c*32 + sr)*CC + h*DH + gsc], &lk[buf][c*32 + sr][sc]);
            async16(&vt[((size_t)((b*HH + h)*DH + c*32 + sr))*TT + kt*64 + gsc], &lv[buf][c*32 + sr][sc]);
        }
    };

#pragma unroll
    for (int c = 0; c < 2; c++)
        async16(&q[(size_t)(b*TT + qt*64 + c*32 + sr)*CC + h*DH + gsc], &lq[c*32 + sr][sc]);
    stageKV(0, 0);
    __syncthreads();

    f32x4 zero = {0.f, 0.f, 0.f, 0.f};
    f32x4 acc_o[4];
    float m_q = -INFINITY, l_q = 0.f;      // state for q-row = wid*16 + l15
#pragma unroll
    for (int ni = 0; ni < 4; ni++) acc_o[ni] = zero;

    const int rowq = wid*16 + l15;
    const int pq = swzp(rowq);

    for (int kt = 0; kt < TT/64; kt++) {
        int cur = kt & 1;
        if (kt + 1 < TT/64) stageKV(cur ^ 1, kt + 1);

        f32x4 s[4];
#pragma unroll
        for (int ni = 0; ni < 4; ni++) s[ni] = zero;
        __builtin_amdgcn_s_setprio(1);
#pragma unroll
        for (int ks = 0; ks < 2; ks++) {
            int lcq = (ks*4 + quad) ^ pq;
            bf16x8 aq = *(const bf16x8*)&lq[rowq][lcq * 8];
            bf16x8 bfr[4];
#pragma unroll
            for (int ni = 0; ni < 4; ni++) {
                int rowk = ni*16 + l15;
                int lck = (ks*4 + quad) ^ swzp(rowk);
                bfr[ni] = *(const bf16x8*)&lk[cur][rowk][lck * 8];
            }
            // SWAPPED: A = K rows, B = Q rows  ->  D[k][q], col(l15) = q
#pragma unroll
            for (int ni = 0; ni < 4; ni++)
                s[ni] = __builtin_amdgcn_mfma_f32_16x16x32_bf16(bfr[ni], aq, s[ni], 0, 0, 0);
        }
        __builtin_amdgcn_s_setprio(0);

        // per-lane online softmax over this lane's 16 scores (k = ni*16 + quad*4 + i)
        float mx = s[0][0];
#pragma unroll
        for (int ni = 0; ni < 4; ni++)
#pragma unroll
            for (int i = 0; i < 4; i++) mx = fmaxf(mx, s[ni][i]);
        mx = fmaxf(mx, __shfl_xor(mx, 16));
        mx = fmaxf(mx, __shfl_xor(mx, 32));
        if (__all(mx - m_q <= 8.0f)) {
            // defer-max: keep m_q, no O-rescale; P bounded by e^8 (bf16-safe)
            float rs = 0.f;
#pragma unroll
            for (int ni = 0; ni < 4; ni++)
#pragma unroll
                for (int i = 0; i < 4; i++) {
                    float p = __expf(s[ni][i] - m_q);
                    s[ni][i] = p;
                    rs += p;
                }
            rs += __shfl_xor(rs, 16);
            rs += __shfl_xor(rs, 32);
            l_q += rs;
        } else {
            float mn = fmaxf(m_q, mx);
            float al = __expf(m_q - mn);
            float rs = 0.f;
#pragma unroll
            for (int ni = 0; ni < 4; ni++)
#pragma unroll
                for (int i = 0; i < 4; i++) {
                    float p = __expf(s[ni][i] - mn);
                    s[ni][i] = p;
                    rs += p;
                }
            rs += __shfl_xor(rs, 16);
            rs += __shfl_xor(rs, 32);
            l_q = l_q * al + rs;
            m_q = mn;

            // broadcast al from lane q'=quad*4+i (lanes 0..15 hold reduced values)
            float alb[4];
#pragma unroll
            for (int i = 0; i < 4; i++) alb[i] = __shfl(al, quad*4 + i);
#pragma unroll
            for (int ni = 0; ni < 4; ni++)
#pragma unroll
                for (int i = 0; i < 4; i++) acc_o[ni][i] *= alb[i];
        }

        // P^T in regs -> lp[q][k]: lane writes 4 u16 per ni, packed 8B
#pragma unroll
        for (int ni = 0; ni < 4; ni++) {
            u16x4 o;
#pragma unroll
            for (int i = 0; i < 4; i++) o[i] = f2bf(s[ni][i]);
            *(u16x4*)&lp[wid][l15][ni*16 + quad*4] = o;
        }

        __builtin_amdgcn_s_setprio(1);
#pragma unroll
        for (int ks = 0; ks < 2; ks++) {
            bf16x8 pa = *(const bf16x8*)&lp[wid][l15][ks*32 + quad*8];
            bf16x8 vb[4];
#pragma unroll
            for (int ni = 0; ni < 4; ni++) {
                int rowv = ni*16 + l15;
                int lcv = (ks*4 + quad) ^ swzp(rowv);
                vb[ni] = *(const bf16x8*)&lv[cur][rowv][lcv * 8];
            }
#pragma unroll
            for (int ni = 0; ni < 4; ni++)
                acc_o[ni] = __builtin_amdgcn_mfma_f32_16x16x32_bf16(pa, vb[ni], acc_o[ni], 0, 0, 0);
        }
        __builtin_amdgcn_s_setprio(0);
        __syncthreads();
    }

    float lb[4];
#pragma unroll
    for (int i = 0; i < 4; i++) lb[i] = __shfl(l_q, quad*4 + i);
#pragma unroll
    for (int i = 0; i < 4; i++) {
        float inv = 1.0f / lb[i];
#pragma unroll
        for (int ni = 0; ni < 4; ni++) {
            int qrow = qt*64 + wid*16 + quad*4 + i;
            int col  = h*DH + ni*16 + l15;
            y[(size_t)(b*TT + qrow)*CC + col] = f2bf(acc_o[ni][i] * inv);
        }
    }
}

extern "C" void kernel_launch(void* const* d_in, const int* in_sizes, int n_in,
                              void* d_out, int out_size, void* d_ws, size_t ws_size,
                              hipStream_t stream) {
    const int*   idx   = (const int*)d_in[0];
    const float* tok   = (const float*)d_in[1];
    const float* pos   = (const float*)d_in[2];
    const float* ln1g  = (const float*)d_in[3];
    const float* ln1b  = (const float*)d_in[4];
    const float* Wq    = (const float*)d_in[5];
    const float* bq    = (const float*)d_in[6];
    const float* Wk    = (const float*)d_in[7];
    const float* bk    = (const float*)d_in[8];
    const float* Wv    = (const float*)d_in[9];
    const float* bv    = (const float*)d_in[10];
    const float* Wp    = (const float*)d_in[11];
    const float* bp    = (const float*)d_in[12];
    const float* ln2g  = (const float*)d_in[13];
    const float* ln2b  = (const float*)d_in[14];
    const float* W1    = (const float*)d_in[15];
    const float* b1    = (const float*)d_in[16];
    const float* W2    = (const float*)d_in[17];
    const float* b2    = (const float*)d_in[18];
    const float* lnfg  = (const float*)d_in[19];
    const float* lnfb  = (const float*)d_in[20];
    const float* Whead = (const float*)d_in[21];

    // ---- workspace layout ----
    float* x  = (float*)d_ws;                       // BT*CC fp32 residual master
    u16* xb   = (u16*)(x + (size_t)BT*CC);          // BT*CC bf16 raw-x copy (LN folded downstream)
    u16* yb   = xb + (size_t)BT*CC;                 // attn output
    u16* R    = yb + (size_t)BT*CC;
    u16* qb   = R;
    u16* kb   = R + (size_t)BT*CC;
    u16* vtb  = R + (size_t)2*BT*CC;
    u16* hb   = R;                                  // BT*FF spans region (q/k/vt dead in MLP)
    u16* w_qkvt = R + (size_t)4*BT*CC;
    u16* w_pt   = w_qkvt + (size_t)2*3*CC*CC;
    u16* w_1t   = w_pt   + (size_t)2*CC*CC;
    u16* w_2t   = w_1t   + (size_t)2*CC*FF;
    u16* w_ht   = w_2t   + (size_t)2*FF*CC;
    float* ucb  = (float*)(w_ht + (size_t)CC*VV);   // 2*8*7680 floats: u/c k-split partials
    float2* sp  = (float2*)(ucb + 2*8*7680);        // BT*8 row-stats partials

    prologue_kernel<<<1840 + BT/2, 256, 0, stream>>>(Wq, Wk, Wv, Wp, W1, W2, Whead,
                                                     ln1g, ln1b, ln2g, ln2b, lnfg, lnfb,
                                                     w_qkvt, w_pt, w_1t, w_2t, w_ht,
                                                     idx, tok, pos, x, xb, ucb, sp);

    // round-4 proven tiles/grids (occupancy-bound regime):
    const int g_qkv  = (3*CC/128) * (BT/64);   // 12*64  = 768  (512t)
    const int g_fc1  = (FF/128)   * (BT/64);   // 16*64  = 1024 (512t)
    const int g_pf   = (CC/64)    * (BT/32);   // 8*128  = 1024 (256t, proj/fc2, 32x64)
    const int g_head = (VV/64)    * (BT/32);   // 1024

    for (int s = 0; s < NSTEPS; s++) {
        for (int l = 0; l < LL; l++) {
            // attention: LN1 folded into QKV GEMM
            gemm_bt_kernel<64,128,512,2,4,0><<<g_qkv, 512, 0, stream>>>(
                xb, w_qkvt + (size_t)l*3*CC*CC, 3*CC, CC,
                bq + l*CC, bk + l*CC, bv + l*CC,
                ucb + l*1536, ucb + 61440 + l*1536, sp, nullptr,
                nullptr, qb, kb, vtb);
            attn_mfma_kernel<<<dim3(TT/64, HH, BB), 256, 0, stream>>>(qb, kb, vtb, yb);
            gemm_bt_kernel<32,64,256,2,2,1><<<g_pf, 256, 0, stream>>>(
                yb, w_pt + (size_t)l*CC*CC, CC, CC,
                bp + l*CC, nullptr, nullptr,
                nullptr, nullptr, nullptr, sp,
                x, xb, nullptr, nullptr);
            // MLP: LN2 folded into fc1 GEMM
            gemm_bt_kernel<64,128,512,2,4,2><<<g_fc1, 512, 0, stream>>>(
                xb, w_1t + (size_t)l*CC*FF, FF, CC,
                b1 + (size_t)l*FF, nullptr, nullptr,
                ucb + 3072 + l*2048, ucb + 61440 + 3072 + l*2048, sp, nullptr,
                nullptr, hb, nullptr, nullptr);
            gemm_bt_kernel<32,64,256,2,2,1><<<g_pf, 256, 0, stream>>>(
                hb, w_2t + (size_t)l*FF*CC, CC, FF,
                b2 + l*CC, nullptr, nullptr,
                nullptr, nullptr, nullptr, sp,
                x, xb, nullptr, nullptr);
        }
    }

    // final LN folded into head GEMM (fp32 logits)
    gemm_bt_kernel<32,64,256,2,2,3><<<g_head, 256, 0, stream>>>(
        xb, w_ht, VV, CC,
        nullptr, nullptr, nullptr,
        ucb + 7168, ucb + 61440 + 7168, sp, nullptr,
        (float*)d_out, nullptr, nullptr, nullptr);
}

// Round 8
// 831.513 us; speedup vs baseline: 1.1212x; 1.0036x over previous
//
#include <hip/hip_runtime.h>
#include <hip/hip_bf16.h>
#include <math.h>

#define BB 8
#define TT 512
#define CC 512
#define HH 8
#define DH 64
#define LL 2
#define VV 512
#define NSTEPS 4
#define BT (BB*TT)
#define FF (4*CC)

typedef unsigned short u16;
typedef __bf16 bf16x8 __attribute__((ext_vector_type(8)));
typedef float f32x4 __attribute__((ext_vector_type(4)));
typedef u16 u16x8 __attribute__((ext_vector_type(8)));
typedef u16 u16x4 __attribute__((ext_vector_type(4)));

// fp32 -> bf16 bits, round-to-nearest-even
static __device__ __forceinline__ u16 f2bf(float f) {
    unsigned int u = __float_as_uint(f);
    unsigned int r = (u + 0x7fffu + ((u >> 16) & 1u)) >> 16;
    return (u16)r;
}

// async global->LDS, 16 bytes per lane (global_load_lds_dwordx4)
static __device__ __forceinline__ void async16(const void* g, void* l) {
    __builtin_amdgcn_global_load_lds((__attribute__((address_space(1))) void*)g,
                                     (__attribute__((address_space(3))) void*)l, 16, 0, 0);
}

// bank swizzle: row r's global chunk g lives at LDS chunk g ^ p(r) (source-side permute).
static __device__ __forceinline__ int swzp(int r) { return (r ^ (r >> 2)) & 7; }

// ---------------- merged prologue ----------------
// blocks [0,1536):    per-layer weight cast+transpose tiles (g folded at pack time)
// blocks [1536,1600): Whead cast+transpose (lnf_g folded)
// blocks [1600,1840): u/c column reductions, k-split x8 -> partials ucb[8][7680] (u), +61440 (c)
// blocks [1840,3888): embedding, 2 rows/block: x fp32, xb bf16, row stats partials
__global__ __launch_bounds__(256)
void prologue_kernel(const float* __restrict__ Wq, const float* __restrict__ Wk,
                     const float* __restrict__ Wv, const float* __restrict__ Wp,
                     const float* __restrict__ W1, const float* __restrict__ W2,
                     const float* __restrict__ Wh,
                     const float* __restrict__ ln1g, const float* __restrict__ ln1b,
                     const float* __restrict__ ln2g, const float* __restrict__ ln2b,
                     const float* __restrict__ lnfg, const float* __restrict__ lnfb,
                     u16* w_qkvt, u16* w_pt, u16* w_1t, u16* w_2t, u16* w_ht,
                     const int* __restrict__ idx, const float* __restrict__ tok,
                     const float* __restrict__ pos, float* __restrict__ x,
                     u16* __restrict__ xb, float* __restrict__ ucb,
                     float2* __restrict__ sp) {
    int bid = blockIdx.x;
    const size_t wcc = (size_t)CC*CC, wcf = (size_t)CC*FF;
    if (bid >= 1840) {
        // ---- embedding: 2 rows per block, vectorized ----
        int eb = bid - 1840;
        int t  = threadIdx.x;
        int r  = t >> 7, c4 = t & 127;
        int row = eb*2 + r;
        int token = idx[row];
        int posrow = row & (TT - 1);
        f32x4 v = ((const f32x4*)(tok + (size_t)token*CC))[c4]
                + ((const f32x4*)(pos + (size_t)posrow*CC))[c4];
        size_t base = (size_t)row*CC;
        ((f32x4*)(x + base))[c4] = v;
        u16x4 o;
#pragma unroll
        for (int j = 0; j < 4; j++) o[j] = f2bf(v[j]);
        *(u16x4*)&xb[base + c4*4] = o;
        float s = v[0]+v[1]+v[2]+v[3];
        float q = v[0]*v[0]+v[1]*v[1]+v[2]*v[2]+v[3]*v[3];
#pragma unroll
        for (int off = 1; off < 64; off <<= 1) { s += __shfl_xor(s, off); q += __shfl_xor(q, off); }
        __shared__ float rs[4], rq[4];
        int wid = t >> 6, lane = t & 63;
        if (lane == 0) { rs[wid] = s; rq[wid] = q; }
        __syncthreads();
        if (t < 16) {
            int r2 = t >> 3, slot = t & 7;
            float2 val = (slot == 0)
                ? make_float2(rs[r2*2] + rs[r2*2+1], rq[r2*2] + rq[r2*2+1])
                : make_float2(0.f, 0.f);
            sp[(size_t)(eb*2 + r2)*8 + slot] = val;
        }
        return;
    }
    if (bid >= 1600) {
        // ---- u/c partials: 240 blocks = 8 k-chunks x 30 col-blocks ----
        int d  = bid - 1600;
        int j  = d & 7;            // k chunk
        int cb = d >> 3;           // column block
        int c  = cb*256 + threadIdx.x;   // 0..7679
        const float* Wsrc; const float* gv; const float* bv2;
        int n, Nd;
        if (c < 3072) {                       // qkv: [l][mat][n]
            int l = c / 1536, w = c % 1536, m = w / 512; n = w % 512; Nd = CC;
            Wsrc = (m == 0 ? Wq : (m == 1 ? Wk : Wv)) + l*wcc;
            gv = ln1g + l*CC; bv2 = ln1b + l*CC;
        } else if (c < 7168) {                // fc1: [l][n]
            int dd = c - 3072, l = dd / 2048; n = dd % 2048; Nd = FF;
            Wsrc = W1 + l*wcf; gv = ln2g + l*CC; bv2 = ln2b + l*CC;
        } else {                              // head
            n = c - 7168; Nd = VV; Wsrc = Wh; gv = lnfg; bv2 = lnfb;
        }
        float su = 0.f, sc = 0.f;
        int k0 = j*64;
#pragma unroll 4
        for (int kk = 0; kk < 64; kk++) {
            float w = Wsrc[(size_t)(k0 + kk)*Nd + n];
            su += gv[k0 + kk]*w; sc += bv2[k0 + kk]*w;
        }
        ucb[j*7680 + c]         = su;
        ucb[61440 + j*7680 + c] = sc;
        return;
    }
    // ---- weight cast + transpose tiles ----
    const float* src; u16* dst; const float* gv = nullptr; int K, N, i0, j0;
    if (bid < 1536) {
        int l = bid / 768, r = bid % 768;
        if (r < 256) {
            int m = r / 64, t = r % 64;
            K = CC; N = CC;
            i0 = (t / 8) * 64; j0 = (t % 8) * 64;
            if      (m == 0) { src = Wq + l*wcc; dst = w_qkvt + (size_t)l*3*wcc;          gv = ln1g + l*CC; }
            else if (m == 1) { src = Wk + l*wcc; dst = w_qkvt + (size_t)l*3*wcc + wcc;    gv = ln1g + l*CC; }
            else if (m == 2) { src = Wv + l*wcc; dst = w_qkvt + (size_t)l*3*wcc + 2*wcc;  gv = ln1g + l*CC; }
            else             { src = Wp + l*wcc; dst = w_pt + (size_t)l*wcc; }
        } else if (r < 512) {
            int t = r - 256;               // W1: [CC][FF] -> [FF][CC]
            K = CC; N = FF;
            i0 = (t / 32) * 64; j0 = (t % 32) * 64;
            src = W1 + l*wcf; dst = w_1t + (size_t)l*wcf; gv = ln2g + l*CC;
        } else {
            int t = r - 512;               // W2: [FF][CC] -> [CC][FF]
            K = FF; N = CC;
            i0 = (t / 8) * 64; j0 = (t % 8) * 64;
            src = W2 + l*wcf; dst = w_2t + (size_t)l*wcf;
        }
    } else {
        int t = bid - 1536;
        K = CC; N = CC;
        i0 = (t / 8) * 64; j0 = (t % 8) * 64;
        src = Wh; dst = w_ht; gv = lnfg;
    }
    __shared__ float tile[64][65];
    __shared__ float gl[64];
    int tt = threadIdx.x;
    int rr = tt >> 2, cg = (tt & 3) * 16;
    if (tt < 64) gl[tt] = gv ? gv[i0 + tt] : 1.0f;
    {
        const float* srow = &src[(size_t)(i0 + rr) * N + j0 + cg];
        f32x4 v[4];
#pragma unroll
        for (int w = 0; w < 4; w++) v[w] = ((const f32x4*)srow)[w];
#pragma unroll
        for (int w = 0; w < 4; w++)
#pragma unroll
            for (int e = 0; e < 4; e++) tile[rr][cg + w*4 + e] = v[w][e];
    }
    __syncthreads();
    u16x8 o0, o1;
#pragma unroll
    for (int i = 0; i < 8; i++) o0[i] = f2bf(tile[cg + i][rr]     * gl[cg + i]);
#pragma unroll
    for (int i = 0; i < 8; i++) o1[i] = f2bf(tile[cg + 8 + i][rr] * gl[cg + 8 + i]);
    u16* drow = &dst[(size_t)(j0 + rr) * K + i0 + cg];
    *(u16x8*)drow       = o0;
    *(u16x8*)(drow + 8) = o1;
}

// ---------------- MFMA GEMM, dbuf BK=64, bank-swizzled, templated wave grid --------------
// out = A[M,K](bf16) @ Bt[N,K]^T.
// EPI 0: LN-folded, fused QKV (q pre-scaled by 0.125*log2e; v transposed)
// EPI 1: bias + residual -> fp32 outf + bf16 outq + stats spout [produces spout]
// EPI 2: LN-folded, bias + exact GELU -> bf16 outq              [consumes]
// EPI 3: LN-folded, plain fp32 out                              [consumes]
template<int BM, int BN, int THREADS, int WROWS, int WCOLS, int EPI>
__global__ __launch_bounds__(THREADS, 6)
void gemm_bt_kernel(const u16* __restrict__ A, const u16* __restrict__ Bt,
                    int N, int K,
                    const float* __restrict__ bias, const float* __restrict__ biask,
                    const float* __restrict__ biasv,
                    const float* __restrict__ uvec, const float* __restrict__ cvec,
                    const float2* __restrict__ spin, float2* __restrict__ spout,
                    float* outf, u16* outq, u16* outk, u16* outvt) {
    constexpr int WTM = BM / WROWS, WTN = BN / WCOLS;
    constexpr int TM = WTM / 16, TN = WTN / 16;
    constexpr bool FOLD = (EPI == 0 || EPI == 2 || EPI == 3);
    static_assert(THREADS == WROWS * WCOLS * 64, "wave grid");
    static_assert((8*BM) % THREADS == 0 && (8*BN) % THREADS == 0, "staging divisibility");
    static_assert(EPI != 1 || (BM == 32 && BN == 64 && WROWS == 2 && WCOLS == 2), "stats layout");
    __shared__ u16 lds_a[2][2][BM][32];
    __shared__ u16 lds_b[2][2][BN][32];
    __shared__ float s_rs[FOLD ? BM : 1], s_mrs[FOLD ? BM : 1];
    __shared__ float psum[EPI == 1 ? 2 : 1][BM], psq[EPI == 1 ? 2 : 1][BM];
    int tid = threadIdx.x;
    int wid = tid >> 6, lane = tid & 63;
    int quad = lane >> 4, l15 = lane & 15;
    int wm = (wid % WROWS) * WTM, wn = (wid / WROWS) * WTN;

    // XCD swizzle: lin&7 picks bm residue -> all bn-blocks of a bm on one XCD
    int NBN = N / BN;
    int lin = blockIdx.x;
    int x8 = lin & 7, slot = lin >> 3;
    int bn = slot % NBN;
    int bm = (slot / NBN) * 8 + x8;

    const size_t a0 = (size_t)bm * BM, b0 = (size_t)bn * BN;

    auto stage = [&](int buf, int kt) {
#pragma unroll
        for (int i = 0; i < (8*BM)/THREADS; i++) {
            int f = tid + i*THREADS;
            int ks2 = f / (4*BM), rem = f % (4*BM);
            int row = rem >> 2, c2 = rem & 3;
            int g = (ks2*4 + c2) ^ swzp(row);
            async16(&A[(a0 + row)*K + kt + g*8], (u16*)lds_a[buf] + (size_t)f*8);
        }
#pragma unroll
        for (int i = 0; i < (8*BN)/THREADS; i++) {
            int f = tid + i*THREADS;
            int ks2 = f / (4*BN), rem = f % (4*BN);
            int row = rem >> 2, c2 = rem & 3;
            int g = (ks2*4 + c2) ^ swzp(row);
            async16(&Bt[(b0 + row)*K + kt + g*8], (u16*)lds_b[buf] + (size_t)f*8);
        }
    };

    f32x4 zero = {0.f, 0.f, 0.f, 0.f};
    f32x4 acc[TM][TN];
#pragma unroll
    for (int mi = 0; mi < TM; mi++)
#pragma unroll
        for (int ni = 0; ni < TN; ni++) acc[mi][ni] = zero;

    stage(0, 0);
    __syncthreads();
    const int NKT = K / 64;
    for (int kt = 0; kt < NKT; kt++) {
        int cur = kt & 1;
        if (kt + 1 < NKT) stage(cur ^ 1, (kt + 1) * 64);
#pragma unroll
        for (int ks = 0; ks < 2; ks++) {
            bf16x8 af[TM], bfr[TN];
#pragma unroll
            for (int mi = 0; mi < TM; mi++) {
                int row = wm + mi*16 + l15;
                int lc = (ks*4 + quad) ^ swzp(row);
                af[mi] = *(const bf16x8*)&lds_a[cur][lc >> 2][row][(lc & 3) * 8];
            }
#pragma unroll
            for (int ni = 0; ni < TN; ni++) {
                int row = wn + ni*16 + l15;
                int lc = (ks*4 + quad) ^ swzp(row);
                bfr[ni] = *(const bf16x8*)&lds_b[cur][lc >> 2][row][(lc & 3) * 8];
            }
#pragma unroll
            for (int mi = 0; mi < TM; mi++)
#pragma unroll
                for (int ni = 0; ni < TN; ni++)
                    acc[mi][ni] = __builtin_amdgcn_mfma_f32_16x16x32_bf16(af[mi], bfr[ni], acc[mi][ni], 0, 0, 0);
        }
        __syncthreads();
    }

    // LN-fold prep: reduce 8 per-row stats partials -> rstd, mu*rstd
    if (FOLD) {
        for (int r = tid; r < BM; r += THREADS) {
            float s = 0.f, q = 0.f;
#pragma unroll
            for (int j = 0; j < 8; j++) { float2 p = spin[(a0 + r)*8 + j]; s += p.x; q += p.y; }
            float mu  = s * (1.0f / CC);
            float var = q * (1.0f / CC) - mu * mu;
            float rstd = rsqrtf(var + 1e-5f);
            s_rs[r] = rstd; s_mrs[r] = mu * rstd;
        }
        __syncthreads();
    }

    float lsum[TM][4], lsq[TM][4];
    if (EPI == 1) {
#pragma unroll
        for (int mi = 0; mi < TM; mi++)
#pragma unroll
            for (int i = 0; i < 4; i++) { lsum[mi][i] = 0.f; lsq[mi][i] = 0.f; }
    }

#pragma unroll
    for (int mi = 0; mi < TM; mi++)
#pragma unroll
        for (int ni = 0; ni < TN; ni++) {
            int col = bn*BN + wn + ni*16 + l15;
            float uc_ = 0.f, cc_ = 0.f;
            if (FOLD) {
#pragma unroll
                for (int j = 0; j < 8; j++) { uc_ += uvec[j*7680 + col]; cc_ += cvec[j*7680 + col]; }
            }
            if (EPI == 0 && (col >> 9) == 2) {
                // v region: 4 consecutive tpos per lane -> one 8B packed store
                int cl = col & 511;
                int row0 = bm*BM + wm + mi*16 + quad*4;
                u16x4 o;
#pragma unroll
                for (int i = 0; i < 4; i++) {
                    int rloc = wm + mi*16 + quad*4 + i;
                    float v = s_rs[rloc]*acc[mi][ni][i] - s_mrs[rloc]*uc_ + cc_ + biasv[cl];
                    o[i] = f2bf(v);
                }
                int bb = row0 >> 9, tpos = row0 & 511, hh = cl >> 6, dh = cl & 63;
                *(u16x4*)&outvt[(((size_t)(bb*8 + hh)*64 + dh) << 9) + tpos] = o;
                continue;
            }
#pragma unroll
            for (int i = 0; i < 4; i++) {
                int rloc = wm + mi*16 + quad*4 + i;
                int row = bm*BM + rloc;
                float v = acc[mi][ni][i];
                if (FOLD) v = s_rs[rloc]*v - s_mrs[rloc]*uc_ + cc_;
                if (EPI == 0) {
                    int region = col >> 9, cl = col & 511;
                    if (region == 0) {
                        // fold 1/sqrt(64) AND log2(e) into q (attn softmax runs in exp2 domain)
                        v = (v + bias[cl]) * 0.18033688011112042f;
                        outq[(size_t)row*512 + cl] = f2bf(v);
                    } else {
                        v += biask[cl];
                        outk[(size_t)row*512 + cl] = f2bf(v);
                    }
                } else if (EPI == 1) {
                    size_t id2 = (size_t)row * N + col;
                    v += bias[col] + outf[id2];
                    outf[id2] = v;
                    outq[id2] = f2bf(v);
                    lsum[mi][i] += v; lsq[mi][i] += v*v;
                } else if (EPI == 2) {
                    v += bias[col];
                    v = 0.5f * v * (1.0f + erff(v * 0.70710678118654752f));
                    outq[(size_t)row * N + col] = f2bf(v);
                } else {
                    outf[(size_t)row * N + col] = v;
                }
            }
        }

    if (EPI == 1) {
        // per-row partial (sum, sumsq) over this block's 64-col span -> spout slot bn
#pragma unroll
        for (int mi = 0; mi < TM; mi++)
#pragma unroll
            for (int i = 0; i < 4; i++) {
                float s = lsum[mi][i], q = lsq[mi][i];
#pragma unroll
                for (int off = 1; off < 16; off <<= 1) { s += __shfl_xor(s, off); q += __shfl_xor(q, off); }
                if (l15 == 0) {
                    int pr = wm + mi*16 + quad*4 + i;
                    psum[wn >> 5][pr] = s; psq[wn >> 5][pr] = q;
                }
            }
        __syncthreads();
        if (tid < BM) {
            spout[(a0 + tid)*8 + bn] = make_float2(psum[0][tid] + psum[1][tid],
                                                   psq[0][tid] + psq[1][tid]);
        }
    }
}

// ---------------- fused MFMA flash attention, QBLK=128, 8 waves, exp2-domain softmax ----
// S^T = mfma(K_frag, Q_frag): lane l15 = q, regs = k. Per-lane softmax in exp2 domain
// (log2e folded into q upstream). K/V staged once per 128 q-rows (half the traffic of
// the 64-row version). defer-max threshold 8*log2e = 11.54.
__global__ __launch_bounds__(512)
void attn_mfma_kernel(const u16* __restrict__ q, const u16* __restrict__ k,
                      const u16* __restrict__ vt, u16* __restrict__ y) {
    __shared__ u16 lq[128][64];
    __shared__ u16 lk[2][64][64];
    __shared__ u16 lv[2][64][64];
    __shared__ u16 lp[8][16][72];
    int qt = blockIdx.x, h = blockIdx.y, b = blockIdx.z;
    int tid = threadIdx.x;
    int wid = tid >> 6, lane = tid & 63;
    int quad = lane >> 4, l15 = lane & 15;
    const int sr = tid >> 3;               // 0..63 (512 threads cover a full 64x64 tile)
    const int sc = (tid & 7) * 8;
    const int gsc = (((tid & 7) ^ swzp(sr)) << 3);

    auto stageKV = [&](int buf, int kt) {
        async16(&k[(size_t)(b*TT + kt*64 + sr)*CC + h*DH + gsc], &lk[buf][sr][sc]);
        async16(&vt[((size_t)((b*HH + h)*DH + sr))*TT + kt*64 + gsc], &lv[buf][sr][sc]);
    };

#pragma unroll
    for (int c = 0; c < 2; c++)
        async16(&q[(size_t)(b*TT + qt*128 + c*64 + sr)*CC + h*DH + gsc], &lq[c*64 + sr][sc]);
    stageKV(0, 0);
    __syncthreads();

    f32x4 zero = {0.f, 0.f, 0.f, 0.f};
    f32x4 acc_o[4];
    float m_q = -INFINITY, l_q = 0.f;      // state for q-row = wid*16 + l15 (exp2 domain)
#pragma unroll
    for (int ni = 0; ni < 4; ni++) acc_o[ni] = zero;

    const int rowq = wid*16 + l15;         // 0..127
    const int pq = swzp(rowq);

    for (int kt = 0; kt < TT/64; kt++) {
        int cur = kt & 1;
        if (kt + 1 < TT/64) stageKV(cur ^ 1, kt + 1);

        f32x4 s[4];
#pragma unroll
        for (int ni = 0; ni < 4; ni++) s[ni] = zero;
        __builtin_amdgcn_s_setprio(1);
#pragma unroll
        for (int ks = 0; ks < 2; ks++) {
            int lcq = (ks*4 + quad) ^ pq;
            bf16x8 aq = *(const bf16x8*)&lq[rowq][lcq * 8];
            bf16x8 bfr[4];
#pragma unroll
            for (int ni = 0; ni < 4; ni++) {
                int rowk = ni*16 + l15;
                int lck = (ks*4 + quad) ^ swzp(rowk);
                bfr[ni] = *(const bf16x8*)&lk[cur][rowk][lck * 8];
            }
            // SWAPPED: A = K rows, B = Q rows  ->  D[k][q], col(l15) = q
#pragma unroll
            for (int ni = 0; ni < 4; ni++)
                s[ni] = __builtin_amdgcn_mfma_f32_16x16x32_bf16(bfr[ni], aq, s[ni], 0, 0, 0);
        }
        __builtin_amdgcn_s_setprio(0);

        // per-lane online softmax (exp2 domain) over this lane's 16 scores
        float mx = s[0][0];
#pragma unroll
        for (int ni = 0; ni < 4; ni++)
#pragma unroll
            for (int i = 0; i < 4; i++) mx = fmaxf(mx, s[ni][i]);
        mx = fmaxf(mx, __shfl_xor(mx, 16));
        mx = fmaxf(mx, __shfl_xor(mx, 32));
        if (__all(mx - m_q <= 11.54f)) {
            // defer-max: keep m_q, no O-rescale; P bounded by 2^11.54 (f32/bf16-safe)
            float rs = 0.f;
#pragma unroll
            for (int ni = 0; ni < 4; ni++)
#pragma unroll
                for (int i = 0; i < 4; i++) {
                    float p = exp2f(s[ni][i] - m_q);
                    s[ni][i] = p;
                    rs += p;
                }
            rs += __shfl_xor(rs, 16);
            rs += __shfl_xor(rs, 32);
            l_q += rs;
        } else {
            float mn = fmaxf(m_q, mx);
            float al = exp2f(m_q - mn);
            float rs = 0.f;
#pragma unroll
            for (int ni = 0; ni < 4; ni++)
#pragma unroll
                for (int i = 0; i < 4; i++) {
                    float p = exp2f(s[ni][i] - mn);
                    s[ni][i] = p;
                    rs += p;
                }
            rs += __shfl_xor(rs, 16);
            rs += __shfl_xor(rs, 32);
            l_q = l_q * al + rs;
            m_q = mn;

            // broadcast al from lane q'=quad*4+i (lanes 0..15 hold reduced values)
            float alb[4];
#pragma unroll
            for (int i = 0; i < 4; i++) alb[i] = __shfl(al, quad*4 + i);
#pragma unroll
            for (int ni = 0; ni < 4; ni++)
#pragma unroll
                for (int i = 0; i < 4; i++) acc_o[ni][i] *= alb[i];
        }

        // P^T in regs -> lp[q][k]: lane writes 4 u16 per ni, packed 8B
#pragma unroll
        for (int ni = 0; ni < 4; ni++) {
            u16x4 o;
#pragma unroll
            for (int i = 0; i < 4; i++) o[i] = f2bf(s[ni][i]);
            *(u16x4*)&lp[wid][l15][ni*16 + quad*4] = o;
        }

        __builtin_amdgcn_s_setprio(1);
#pragma unroll
        for (int ks = 0; ks < 2; ks++) {
            bf16x8 pa = *(const bf16x8*)&lp[wid][l15][ks*32 + quad*8];
            bf16x8 vb[4];
#pragma unroll
            for (int ni = 0; ni < 4; ni++) {
                int rowv = ni*16 + l15;
                int lcv = (ks*4 + quad) ^ swzp(rowv);
                vb[ni] = *(const bf16x8*)&lv[cur][rowv][lcv * 8];
            }
#pragma unroll
            for (int ni = 0; ni < 4; ni++)
                acc_o[ni] = __builtin_amdgcn_mfma_f32_16x16x32_bf16(pa, vb[ni], acc_o[ni], 0, 0, 0);
        }
        __builtin_amdgcn_s_setprio(0);
        __syncthreads();
    }

    float lb[4];
#pragma unroll
    for (int i = 0; i < 4; i++) lb[i] = __shfl(l_q, quad*4 + i);
#pragma unroll
    for (int i = 0; i < 4; i++) {
        float inv = 1.0f / lb[i];
#pragma unroll
        for (int ni = 0; ni < 4; ni++) {
            int qrow = qt*128 + wid*16 + quad*4 + i;
            int col  = h*DH + ni*16 + l15;
            y[(size_t)(b*TT + qrow)*CC + col] = f2bf(acc_o[ni][i] * inv);
        }
    }
}

extern "C" void kernel_launch(void* const* d_in, const int* in_sizes, int n_in,
                              void* d_out, int out_size, void* d_ws, size_t ws_size,
                              hipStream_t stream) {
    const int*   idx   = (const int*)d_in[0];
    const float* tok   = (const float*)d_in[1];
    const float* pos   = (const float*)d_in[2];
    const float* ln1g  = (const float*)d_in[3];
    const float* ln1b  = (const float*)d_in[4];
    const float* Wq    = (const float*)d_in[5];
    const float* bq    = (const float*)d_in[6];
    const float* Wk    = (const float*)d_in[7];
    const float* bk    = (const float*)d_in[8];
    const float* Wv    = (const float*)d_in[9];
    const float* bv    = (const float*)d_in[10];
    const float* Wp    = (const float*)d_in[11];
    const float* bp    = (const float*)d_in[12];
    const float* ln2g  = (const float*)d_in[13];
    const float* ln2b  = (const float*)d_in[14];
    const float* W1    = (const float*)d_in[15];
    const float* b1    = (const float*)d_in[16];
    const float* W2    = (const float*)d_in[17];
    const float* b2    = (const float*)d_in[18];
    const float* lnfg  = (const float*)d_in[19];
    const float* lnfb  = (const float*)d_in[20];
    const float* Whead = (const float*)d_in[21];

    // ---- workspace layout ----
    float* x  = (float*)d_ws;                       // BT*CC fp32 residual master
    u16* xb   = (u16*)(x + (size_t)BT*CC);          // BT*CC bf16 raw-x copy (LN folded downstream)
    u16* yb   = xb + (size_t)BT*CC;                 // attn output
    u16* R    = yb + (size_t)BT*CC;
    u16* qb   = R;
    u16* kb   = R + (size_t)BT*CC;
    u16* vtb  = R + (size_t)2*BT*CC;
    u16* hb   = R;                                  // BT*FF spans region (q/k/vt dead in MLP)
    u16* w_qkvt = R + (size_t)4*BT*CC;
    u16* w_pt   = w_qkvt + (size_t)2*3*CC*CC;
    u16* w_1t   = w_pt   + (size_t)2*CC*CC;
    u16* w_2t   = w_1t   + (size_t)2*CC*FF;
    u16* w_ht   = w_2t   + (size_t)2*FF*CC;
    float* ucb  = (float*)(w_ht + (size_t)CC*VV);   // 2*8*7680 floats: u/c k-split partials
    float2* sp  = (float2*)(ucb + 2*8*7680);        // BT*8 row-stats partials

    prologue_kernel<<<1840 + BT/2, 256, 0, stream>>>(Wq, Wk, Wv, Wp, W1, W2, Whead,
                                                     ln1g, ln1b, ln2g, ln2b, lnfg, lnfb,
                                                     w_qkvt, w_pt, w_1t, w_2t, w_ht,
                                                     idx, tok, pos, x, xb, ucb, sp);

    // round-4 proven tiles/grids (occupancy-bound regime):
    const int g_qkv  = (3*CC/128) * (BT/64);   // 12*64  = 768  (512t)
    const int g_fc1  = (FF/128)   * (BT/64);   // 16*64  = 1024 (512t)
    const int g_pf   = (CC/64)    * (BT/32);   // 8*128  = 1024 (256t, proj/fc2, 32x64)
    const int g_head = (VV/64)    * (BT/32);   // 1024

    for (int s = 0; s < NSTEPS; s++) {
        for (int l = 0; l < LL; l++) {
            // attention: LN1 folded into QKV GEMM
            gemm_bt_kernel<64,128,512,2,4,0><<<g_qkv, 512, 0, stream>>>(
                xb, w_qkvt + (size_t)l*3*CC*CC, 3*CC, CC,
                bq + l*CC, bk + l*CC, bv + l*CC,
                ucb + l*1536, ucb + 61440 + l*1536, sp, nullptr,
                nullptr, qb, kb, vtb);
            attn_mfma_kernel<<<dim3(TT/128, HH, BB), 512, 0, stream>>>(qb, kb, vtb, yb);
            gemm_bt_kernel<32,64,256,2,2,1><<<g_pf, 256, 0, stream>>>(
                yb, w_pt + (size_t)l*CC*CC, CC, CC,
                bp + l*CC, nullptr, nullptr,
                nullptr, nullptr, nullptr, sp,
                x, xb, nullptr, nullptr);
            // MLP: LN2 folded into fc1 GEMM
            gemm_bt_kernel<64,128,512,2,4,2><<<g_fc1, 512, 0, stream>>>(
                xb, w_1t + (size_t)l*CC*FF, FF, CC,
                b1 + (size_t)l*FF, nullptr, nullptr,
                ucb + 3072 + l*2048, ucb + 61440 + 3072 + l*2048, sp, nullptr,
                nullptr, hb, nullptr, nullptr);
            gemm_bt_kernel<32,64,256,2,2,1><<<g_pf, 256, 0, stream>>>(
                hb, w_2t + (size_t)l*FF*CC, CC, FF,
                b2 + l*CC, nullptr, nullptr,
                nullptr, nullptr, nullptr, sp,
                x, xb, nullptr, nullptr);
        }
    }

    // final LN folded into head GEMM (fp32 logits)
    gemm_bt_kernel<32,64,256,2,2,3><<<g_head, 256, 0, stream>>>(
        xb, w_ht, VV, CC,
        nullptr, nullptr, nullptr,
        ucb + 7168, ucb + 61440 + 7168, sp, nullptr,
        (float*)d_out, nullptr, nullptr, nullptr);
}